// Round 11
// baseline (98.756 us; speedup 1.0000x reference)
//
#include <hip/hip_runtime.h>
#include <hip/hip_bf16.h>
#include <math.h>

#define C 8
#define K 128
#define S 64
#define L 2048
#define NB 64
#define W (L - S + 1)   // 1985
#define TW 128
#define NTW 16
#define XCS 200         // xcop stride (shorts); mult of 4 -> 8B-aligned b64 reads
#define XFS 200         // fp32 x scratch stride (192 data + 8 zero pad)

typedef __attribute__((ext_vector_type(8))) short bf16x8;
typedef __attribute__((ext_vector_type(4))) short short4v;
typedef __attribute__((ext_vector_type(4))) float f32x4;
typedef __attribute__((ext_vector_type(16))) float f32x16;

__device__ __forceinline__ unsigned short f2bf(float f) {
  unsigned int u = __float_as_uint(f);
  u += 0x7FFFu + ((u >> 16) & 1u);   // RNE
  return (unsigned short)(u >> 16);
}

// packed f32x2 -> bf16x2 (v_cvt_pk_bf16_f32 on gfx950)
__device__ __forceinline__ unsigned int pkbf(float a, float b) {
  __hip_bfloat162 h = __float22bfloat162_rn(make_float2(a, b));
  return *reinterpret_cast<unsigned int*>(&h);
}

// full-wave ONLY (R8 lesson: lane-predicated global_load_lds explodes traffic)
__device__ __forceinline__ void gll16(const void* g, void* l) {
  __builtin_amdgcn_global_load_lds((const __attribute__((address_space(1))) void*)g,
                                   (__attribute__((address_space(3))) void*)l, 16, 0, 0);
}

// prep: z-normalize shapelets -> bf16 * (-2) in 32x32x16 B-fragment order;
// B[k][n]: n = lane&31, k_local = ((lane>>5)*8 + j); ks = s>>4.
// idx = c*8192 + (k>>5)*2048 + ks*512 + lane'*8 + j,  lane' = ((s>>3)&1)*32 + (k&31)
__global__ __launch_bounds__(256) void prep_kernel(const float* __restrict__ sh,
                                                   unsigned short* __restrict__ shzB,
                                                   float* __restrict__ sqs,
                                                   float* __restrict__ out) {
  int tid = blockIdx.x * 256 + threadIdx.x;
  if (tid < NB * K) out[tid] = __int_as_float(0x7F800000);
  int gid = blockIdx.x * 4 + (threadIdx.x >> 6);  // c*K + k
  int lane = threadIdx.x & 63;                    // = s
  float v = sh[(size_t)gid * S + lane];
  float s1 = v, s2 = v * v;
#pragma unroll
  for (int off = 32; off > 0; off >>= 1) {
    s1 += __shfl_down(s1, off);
    s2 += __shfl_down(s2, off);
  }
  s1 = __shfl(s1, 0);
  s2 = __shfl(s2, 0);
  float mu = s1 * (1.0f / S);
  float sd = sqrtf(fmaxf(s2 * (1.0f / S) - mu * mu, 0.0f));
  float z = (v - mu) / sd;
  int c = gid >> 7, k = gid & (K - 1), s = lane;
  int idx = c * 8192 + (k >> 5) * 2048 + (s >> 4) * 512 +
            ((((s >> 3) & 1) * 32 + (k & 31)) * 8) + (s & 7);
  shzB[idx] = f2bf(-2.0f * z);   // bake the -2 of d2 = sqx + sqs - 2*cross
  float z2 = z * z;
#pragma unroll
  for (int off = 32; off > 0; off >>= 1) z2 += __shfl_down(z2, off);
  if (lane == 0) sqs[gid] = z2;
}

// main: block = 128w x 128k, 256 threads = 4 waves, wave tile 64w x 64k via
// 2x2 grid of 32x32x16 MFMAs. LDS bytes/output-elem drops 14 -> 6 (the R10
// binder). B full-K double-buffered; ONE barrier per channel; accumulator
// region barrier-free per channel (dsum crosses barriers, acc does not).
__global__ __launch_bounds__(256, 3) void main_kernel(const float* __restrict__ x,
                                                      const unsigned short* __restrict__ shzB,
                                                      const float* __restrict__ sqs,
                                                      int* __restrict__ out) {
  __shared__ __align__(16) unsigned short bbuf[2][8192];   // 32 KB B dbuf (16 KB = full K per ch)
  __shared__ __align__(16) unsigned short xcop[C][4][XCS]; // 12.8 KB: 4 shifted bf16 copies
  __shared__ __align__(16) float sqx[C][TW];               // 4 KB
  __shared__ __align__(16) float sqsl[C * K];              // 4 KB

  const int t = threadIdx.x;
  const int lane = t & 63;
  const int wave = t >> 6;     // 0..3
  const int wgrp = wave & 1;   // w-offset 64
  const int kgrp = wave >> 1;  // k-offset 64
  const int m = lane & 31;     // MFMA row/col within 32
  const int h = lane >> 5;     // K-half
  const int n = blockIdx.y;
  const int w0 = blockIdx.x * TW;
  const float* xn = x + (size_t)n * C * L;

  // ---- stage fp32 x segment (8 ch x 192, stride 200, zero-padded) ----
  float* xf = (float*)&bbuf[0][0];  // 1600 floats, dies before B[0] load
#pragma unroll
  for (int j = 0; j < 7; ++j) {
    int s = j * 256 + t;
    if (s < C * XFS) {
      int c = s / XFS, e = s - c * XFS;
      int g = w0 + e;
      xf[s] = (e < 192 && g < L) ? xn[c * L + g] : 0.0f;
    }
  }
  // ---- sqs -> LDS ----
  sqsl[t] = sqs[t];
  sqsl[t + 256] = sqs[t + 256];
  sqsl[t + 512] = sqs[t + 512];
  sqsl[t + 768] = sqs[t + 768];
  __syncthreads();

  // ---- build 4 shifted bf16 copies: 8c x 4r x 96 dwords over 256 threads ----
#pragma unroll
  for (int j = 0; j < 12; ++j) {
    int idx = j * 256 + t;
    int c = idx / 384, rem = idx - c * 384;
    int r = rem / 96, i2 = rem - r * 96;
    int i = i2 * 2;
    *(unsigned int*)&xcop[c][r][i] = pkbf(xf[c * XFS + i + r], xf[c * XFS + i + r + 1]);
  }
  // ---- sliding-window fp32 sqx: thread -> (c, 4 consecutive w) ----
  {
    int c = t >> 5, wl = (t & 31) * 4;
    const float* xr = xf + c * XFS;
    float p0 = 0.f, p1 = 0.f, p2 = 0.f, p3 = 0.f;
#pragma unroll
    for (int si = 0; si < S; si += 4) {
      float v0 = xr[wl + si], v1 = xr[wl + si + 1], v2 = xr[wl + si + 2], v3 = xr[wl + si + 3];
      p0 = fmaf(v0, v0, p0); p1 = fmaf(v1, v1, p1);
      p2 = fmaf(v2, v2, p2); p3 = fmaf(v3, v3, p3);
    }
    float s0 = (p0 + p1) + (p2 + p3);
    sqx[c][wl] = s0;
#pragma unroll
    for (int q = 1; q < 4; ++q) {
      float a = xr[wl + S - 1 + q], b = xr[wl + q - 1];
      s0 += a * a - b * b;
      sqx[c][wl + q] = s0;
    }
  }
  __syncthreads();  // xf dead -> bbuf[0] free for B

  // ---- B channel 0 into bbuf[0]: 16 KB over 256 threads = 4 x 16B ----
#pragma unroll
  for (int i = 0; i < 4; ++i)
    gll16(shzB + i * 2048 + t * 8, &bbuf[0][i * 2048 + wave * 512]);

  f32x16 dsum[2][2];
#pragma unroll
  for (int a = 0; a < 2; ++a)
#pragma unroll
    for (int b = 0; b < 2; ++b)
#pragma unroll
      for (int e = 0; e < 16; ++e) dsum[a][b][e] = 0.0f;

  const int r4 = m & 3;

  for (int c = 0; c < C; ++c) {
    __syncthreads();  // B[c] ready in bbuf[c&1] (drains prefetch vmcnt)
    if (c + 1 < C) {  // prefetch next channel into the other buffer
#pragma unroll
      for (int i = 0; i < 4; ++i)
        gll16(shzB + (c + 1) * 8192 + i * 2048 + t * 8,
              &bbuf[(c + 1) & 1][i * 2048 + wave * 512]);
    }
    const unsigned short* bb = bbuf[c & 1];

    // B fragments for this channel: 2 ktiles x 4 ksteps (cached in regs)
    bf16x8 bfr[8];
#pragma unroll
    for (int kt = 0; kt < 2; ++kt)
#pragma unroll
      for (int ks = 0; ks < 4; ++ks)
        bfr[kt * 4 + ks] = *(const bf16x8*)(bb + (kgrp * 2 + kt) * 2048 + ks * 512 + lane * 8);

    float sqv0 = sqsl[c * K + kgrp * 64 + m];
    float sqv1 = sqsl[c * K + kgrp * 64 + 32 + m];

#pragma unroll
    for (int wsub = 0; wsub < 2; ++wsub) {
      const int wb = wgrp * 64 + wsub * 32;
      // sqx rows for this 32-row band: row = (e&3) + 8*(e>>2) + 4*h
      f32x4 sxv[4];
#pragma unroll
      for (int g = 0; g < 4; ++g)
        sxv[g] = *(const f32x4*)&sqx[c][wb + 8 * g + 4 * h];
      // A fragments (4 ksteps, cached; 4-lane broadcast within m-groups)
      const unsigned short* xc = &xcop[c][r4][0];
      bf16x8 af[4];
#pragma unroll
      for (int ks = 0; ks < 4; ++ks) {
        int base = wb + (m - r4) + ks * 16 + 8 * h;  // mult of 4 -> 8B aligned
        short4v lo = *(const short4v*)(xc + base);
        short4v hi = *(const short4v*)(xc + base + 4);
        af[ks] = __builtin_shufflevector(lo, hi, 0, 1, 2, 3, 4, 5, 6, 7);
      }
#pragma unroll
      for (int kt = 0; kt < 2; ++kt) {
        f32x16 acc;
        float sq = kt ? sqv1 : sqv0;
#pragma unroll
        for (int g = 0; g < 4; ++g)
#pragma unroll
          for (int i = 0; i < 4; ++i) acc[g * 4 + i] = sxv[g][i] + sq;
#pragma unroll
        for (int ks = 0; ks < 4; ++ks)
          acc = __builtin_amdgcn_mfma_f32_32x32x16_bf16(af[ks], bfr[kt * 4 + ks], acc, 0, 0, 0);
#pragma unroll
        for (int e = 0; e < 16; ++e)
          dsum[wsub][kt][e] += __builtin_amdgcn_sqrtf(fmaxf(acc[e], 0.0f));
      }
    }
  }

  // min over w (regs + h-pair shuffle), one atomicMin per k from lanes 0..31
  const float INF = __int_as_float(0x7F800000);
#pragma unroll
  for (int kt = 0; kt < 2; ++kt) {
    float mv = INF;
#pragma unroll
    for (int wsub = 0; wsub < 2; ++wsub)
#pragma unroll
      for (int e = 0; e < 16; ++e) {
        int w = w0 + wgrp * 64 + wsub * 32 + (e & 3) + 8 * (e >> 2) + 4 * h;
        mv = (w < W) ? fminf(mv, dsum[wsub][kt][e]) : mv;
      }
    mv = fminf(mv, __shfl_xor(mv, 32));
    if (h == 0)
      atomicMin(&out[n * K + kgrp * 64 + kt * 32 + m], __float_as_int(mv));
  }
}

extern "C" void kernel_launch(void* const* d_in, const int* in_sizes, int n_in,
                              void* d_out, int out_size, void* d_ws, size_t ws_size,
                              hipStream_t stream) {
  const float* x = (const float*)d_in[0];    // (64, 8, 2048) fp32
  const float* sh = (const float*)d_in[1];   // (8, 128, 64) fp32
  float* out = (float*)d_out;                // (64, 1, 128) fp32
  unsigned short* shzB = (unsigned short*)d_ws;             // 128 KB bf16 B-frag layout (scaled -2)
  float* sqs = (float*)((char*)d_ws + C * K * S * 2);       // 4 KB fp32

  prep_kernel<<<256, 256, 0, stream>>>(sh, shzB, sqs, out);
  main_kernel<<<dim3(NTW, NB), 256, 0, stream>>>(x, shzB, sqs, (int*)out);
}